// Round 6
// baseline (601.596 us; speedup 1.0000x reference)
//
#include <hip/hip_runtime.h>
#include <math.h>

#define NPTS 1024
#define S_   512
#define T_   8
#define K_   32
#define B_   2

typedef short bf16x8 __attribute__((ext_vector_type(8)));
typedef short short4v __attribute__((ext_vector_type(4)));
typedef float f32x4 __attribute__((ext_vector_type(4)));

static __device__ __forceinline__ short f2bf(float f) {
    unsigned u = __float_as_uint(f);
    unsigned r = (u + 0x7FFFu + ((u >> 16) & 1u)) >> 16;   // RNE
    return (short)r;
}

// ---- DPP wave-64 max reduction helper (result valid in lane 63) -----------
template <int CTRL>
static __device__ __forceinline__ float dppmaxf(float x) {
    int mv = __builtin_amdgcn_update_dpp(0, __float_as_int(x), CTRL, 0xF, 0xF, true);
    return fmaxf(x, __int_as_float(mv));
}
static __device__ __forceinline__ unsigned wavemax_bits_f(float x) {
    x = dppmaxf<0x111>(x); x = dppmaxf<0x112>(x);
    x = dppmaxf<0x114>(x); x = dppmaxf<0x118>(x);
    x = dppmaxf<0x142>(x); x = dppmaxf<0x143>(x);
    return (unsigned)__builtin_amdgcn_readlane(__float_as_int(x), 63);
}

// ---------------------------------------------------------------------------
// Kernel 1: FPS, 4-wave version. n = tid*4 + j (lane order == n order).
// Per iter: fused dist+lane-argmax -> 1 DPP chain + ballot/ffs -> candidate
// (x,y,z,val,n) to LDS slot -> barrier -> uniform 4-way serial reduce.
// Center coords come out of the reduction (no sc[far] re-read).
// Exact-bits argmax, first-occurrence tie-break == jnp.argmax.
// ---------------------------------------------------------------------------
__global__ __launch_bounds__(256) void fps_kernel(const float* __restrict__ xyz,
                                                  int* __restrict__ fidx)
{
    int b    = blockIdx.x;
    int tid  = threadIdx.x;
    int lane = tid & 63;
    int wv   = tid >> 6;
    const float* bx = xyz + (size_t)b * (T_ * 3 * NPTS);   // frame 0 of batch b
    float4 px = ((const float4*)(bx))[tid];
    float4 py = ((const float4*)(bx + NPTS))[tid];
    float4 pz = ((const float4*)(bx + 2 * NPTS))[tid];
    float mind[4] = {1e10f, 1e10f, 1e10f, 1e10f};
    __shared__ float4 cslot[2][4];
    __shared__ int    nslot[2][4];

    int far = 0;
    float cx = bx[0], cy = bx[NPTS], cz = bx[2 * NPTS];

    for (int it = 0; it < S_; ++it) {
        if (tid == 0) fidx[b * S_ + it] = far;
        float lmax = -1.0f; int lj = 0;
#pragma unroll
        for (int j = 0; j < 4; ++j) {
            float pxj = (j == 0) ? px.x : (j == 1) ? px.y : (j == 2) ? px.z : px.w;
            float pyj = (j == 0) ? py.x : (j == 1) ? py.y : (j == 2) ? py.z : py.w;
            float pzj = (j == 0) ? pz.x : (j == 1) ? pz.y : (j == 2) ? pz.z : pz.w;
            float dx = __fsub_rn(pxj, cx);
            float dy = __fsub_rn(pyj, cy);
            float dz = __fsub_rn(pzj, cz);
            float d  = __fmaf_rn(dz, dz, __fmaf_rn(dy, dy, __fmul_rn(dx, dx)));
            float mn = fminf(mind[j], d);
            mind[j] = mn;
            if (mn > lmax) { lmax = mn; lj = j; }   // strict > keeps smallest j
        }
        unsigned maxb = wavemax_bits_f(lmax);
        unsigned long long mask = __ballot(__float_as_uint(lmax) == maxb);
        int l0 = __ffsll((long long)mask) - 1;      // lowest lane = smallest n
        // candidate coords (select own lj)
        float sx = (lj & 2) ? ((lj & 1) ? px.w : px.z) : ((lj & 1) ? px.y : px.x);
        float sy = (lj & 2) ? ((lj & 1) ? py.w : py.z) : ((lj & 1) ? py.y : py.x);
        float sz = (lj & 2) ? ((lj & 1) ? pz.w : pz.z) : ((lj & 1) ? pz.y : pz.x);
        int   nn = tid * 4 + lj;
        int bufi = it & 1;
        if (lane == l0) {
            cslot[bufi][wv] = make_float4(sx, sy, sz, __uint_as_float(maxb));
            nslot[bufi][wv] = nn;
        }
        __syncthreads();
        float4 s0 = cslot[bufi][0];
        unsigned bv = __float_as_uint(s0.w);
        float bxx = s0.x, byy = s0.y, bzz = s0.z;
        int bn = nslot[bufi][0];
#pragma unroll
        for (int w2 = 1; w2 < 4; ++w2) {
            float4 sw = cslot[bufi][w2];
            int nw = nslot[bufi][w2];
            unsigned uv = __float_as_uint(sw.w);
            bool bet = (uv > bv) || (uv == bv && nw < bn);
            if (bet) { bv = uv; bxx = sw.x; byy = sw.y; bzz = sw.z; bn = nw; }
        }
        far = bn; cx = bxx; cy = byy; cz = bzz;
    }
}

// ---------------------------------------------------------------------------
// Kernel 1b: transpose points [bt][64][1024] f32 -> ptsT [bt][1024][64] bf16.
// ---------------------------------------------------------------------------
__global__ __launch_bounds__(256) void transpose_points(
    const float* __restrict__ pts, short* __restrict__ ptsT)
{
    int nt = blockIdx.x;      // 16 tiles of 64 points
    int bt = blockIdx.y;
    __shared__ float tile[64][65];
    int tid = threadIdx.x;
    for (int e = tid; e < 4096; e += 256) {
        int ci = e >> 6, nn = e & 63;
        tile[ci][nn] = pts[((size_t)bt * 64 + ci) * NPTS + nt * 64 + nn];
    }
    __syncthreads();
    for (int e = tid; e < 4096; e += 256) {
        int nn = e >> 6, ci = e & 63;
        ptsT[((size_t)bt * NPTS + nt * 64 + nn) * 64 + ci] = f2bf(tile[ci][nn]);
    }
}

// ---------------------------------------------------------------------------
// Kernel 2: ball query per (bt, s). 1 wave per block (unchanged, verified).
// ---------------------------------------------------------------------------
__global__ void ballquery_kernel(const float* __restrict__ xyz,
                                 const int* __restrict__ fidx,
                                 int* __restrict__ gidx,
                                 float* __restrict__ newxyz,
                                 float* __restrict__ out0)
{
    int s    = blockIdx.x;
    int bt   = blockIdx.y;
    int b    = bt >> 3;
    int lane = threadIdx.x;
    const float* bx = xyz + (size_t)bt * 3 * NPTS;
    int fid = fidx[b * S_ + s];
    float nx = bx[fid], ny = bx[NPTS + fid], nz = bx[2 * NPTS + fid];
    if (lane < 3) {
        float vv = (lane == 0) ? nx : ((lane == 1) ? ny : nz);
        out0[(bt * 3 + lane) * S_ + s]   = vv;   // [B,t,3,S]
        newxyz[(bt * S_ + s) * 3 + lane] = vv;
    }
    float A = __fmaf_rn(nz, nz, __fmaf_rn(ny, ny, __fmul_rn(nx, nx)));
    const float R2 = (float)(0.2 * 0.2);
    int* g = gidx + (size_t)(bt * S_ + s) * K_;
    int count = 0, firstIdx = -1;
    for (int j = 0; j < 16; ++j) {
        if (count >= K_) break;
        int n = j * 64 + lane;
        float x = bx[n], y = bx[NPTS + n], z = bx[2 * NPTS + n];
        float Bn = __fmaf_rn(z, z, __fmaf_rn(y, y, __fmul_rn(x, x)));
        float C  = __fmaf_rn(nz, z, __fmaf_rn(ny, y, __fmul_rn(nx, x)));
        float sq = __fsub_rn(__fadd_rn(A, Bn), __fmul_rn(2.0f, C));
        bool valid = !(sq > R2);
        unsigned long long mb = __ballot(valid);
        if (valid) {
            int pos = count + __popcll(mb & ((1ull << lane) - 1ull));
            if (pos < K_) g[pos] = n;
        }
        if (firstIdx < 0 && mb) firstIdx = j * 64 + (__ffsll((long long)mb) - 1);
        count += __popcll(mb);
    }
    if (count < K_) {
        for (int p = count + lane; p < K_; p += 64) g[p] = firstIdx;
    }
}

// ---------------------------------------------------------------------------
// MFMA conv (verified). GATHER reads bf16 rows from ptsT; layer-1 channel
// order is [points 64][gxyz 3][pad], weights permuted to match.
// ---------------------------------------------------------------------------
template <int CI, int CIp, int NK, bool GATHER, bool POOL>
__global__ __launch_bounds__(256) void conv_mfma(
    const short* __restrict__ actIn,
    const float* __restrict__ xyz, const short* __restrict__ ptsT,
    const int* __restrict__ gidx, const float* __restrict__ newxyz,
    const float* __restrict__ w,  const float* __restrict__ bb,
    const float* __restrict__ gg, const float* __restrict__ be,
    const float* __restrict__ mm, const float* __restrict__ vv,
    short* __restrict__ actOut, float* __restrict__ outPool)
{
    __shared__ __align__(16) short wsh[4 * 64 * CIp];
    __shared__ __align__(16) short xs[256 * CIp];
    int s = blockIdx.x, b = blockIdx.y;
    int co_base = blockIdx.z * 64;
    int tid = threadIdx.x;

    // ---- stage weights (fp32 -> bf16), layout [dt][co][ci'], zero-pad ----
    for (int e = tid; e < 4 * 64 * CIp; e += 256) {
        int dt = e / (64 * CIp);
        int rem = e - dt * (64 * CIp);
        int co = rem / CIp;
        int ci = rem - co * CIp;
        float val = 0.0f;
        if (GATHER) {
            int cref = (ci < 64) ? (ci + 3) : ((ci < 67) ? (ci - 64) : -1);
            if (cref >= 0)
                val = w[(((size_t)(co_base + co)) * CI + cref) * 4 + dt];
        } else {
            if (ci < CI)
                val = w[(((size_t)(co_base + co)) * CI + ci) * 4 + dt];
        }
        wsh[e] = f2bf(val);
    }

    // ---- stage x tile: xs[col][ci'] bf16, col = t*32 + k ----
    {
        int col = tid;
        short* xrow = &xs[col * CIp];
        if (GATHER) {
            int k = col & 31, tt = col >> 5;
            int bt = b * T_ + tt;
            int idx = gidx[((size_t)bt * S_ + s) * K_ + k];
            const short* prow = ptsT + ((size_t)bt * NPTS + idx) * 64;
#pragma unroll
            for (int c = 0; c < 8; ++c)   // 64 bf16 point channels
                ((int4*)xrow)[c] = ((const int4*)prow)[c];
            const float* nxp = &newxyz[((size_t)bt * S_ + s) * 3];
#pragma unroll
            for (int ci = 0; ci < 3; ++ci)
                xrow[64 + ci] = f2bf(xyz[(size_t)(bt * 3 + ci) * NPTS + idx] - nxp[ci]);
            for (int ci = 67; ci < CIp; ++ci) xrow[ci] = 0;
        } else {
            const short* src = actIn + (((size_t)b * S_ + s) * 256 + col) * 64;
#pragma unroll
            for (int c = 0; c < 8; ++c)   // 8 x 16B = 64 bf16 channels
                ((int4*)xrow)[c] = ((const int4*)src)[c];
            for (int ci = 64; ci < CIp; ++ci) xrow[ci] = 0;
        }
    }
    __syncthreads();

    int lane = tid & 63;
    int wv   = tid >> 6;          // wave id 0..3 -> co stripe
    int l16  = lane & 15;
    int lq   = lane >> 4;

    f32x4 acc[16];
#pragma unroll
    for (int nb = 0; nb < 16; ++nb) acc[nb] = (f32x4){0.f, 0.f, 0.f, 0.f};

#pragma unroll
    for (int ks = 0; ks < NK; ++ks) {
        bf16x8 afr[4];
#pragma unroll
        for (int dt = 0; dt < 4; ++dt)
            afr[dt] = *(const bf16x8*)&wsh[(dt * 64 + wv * 16 + l16) * CIp + ks * 32 + lq * 8];
        bf16x8 bfr[16];
#pragma unroll
        for (int cb = 0; cb < 16; ++cb)
            bfr[cb] = *(const bf16x8*)&xs[(cb * 16 + l16) * CIp + ks * 32 + lq * 8];
#pragma unroll
        for (int dt = 0; dt < 4; ++dt) {
#pragma unroll
            for (int nb = 0; nb < 16; ++nb) {
                int cb = nb + (dt - 1) * 2;
                if (cb >= 0 && cb < 16)
                    acc[nb] = __builtin_amdgcn_mfma_f32_16x16x32_bf16(
                        afr[dt], bfr[cb], acc[nb], 0, 0, 0);
            }
        }
    }

    // ---- epilogue: BN + ReLU (+ pool) ----
    float sc[4], c2[4];
#pragma unroll
    for (int j = 0; j < 4; ++j) {
        int co = co_base + wv * 16 + lq * 4 + j;
        float scv = gg[co] / sqrtf(vv[co] + 1e-5f);
        sc[j] = scv;
        c2[j] = (bb[co] - mm[co]) * scv + be[co];
    }

    if (POOL) {
#pragma unroll
        for (int nbp = 0; nbp < 8; ++nbp) {       // t = nbp
#pragma unroll
            for (int j = 0; j < 4; ++j) {
                float v0 = fmaxf(acc[2 * nbp][j] * sc[j] + c2[j], 0.0f);
                float v1 = fmaxf(acc[2 * nbp + 1][j] * sc[j] + c2[j], 0.0f);
                float v = fmaxf(v0, v1);
#pragma unroll
                for (int off = 1; off < 16; off <<= 1)
                    v = fmaxf(v, __shfl_xor(v, off));
                if (l16 == 0) {
                    int co = co_base + wv * 16 + lq * 4 + j;
                    outPool[((size_t)(b * T_ + nbp) * 128 + co) * S_ + s] = v;
                }
            }
        }
    } else {
#pragma unroll
        for (int nb = 0; nb < 16; ++nb) {
            int col = nb * 16 + l16;
            short4v pk;
#pragma unroll
            for (int j = 0; j < 4; ++j)
                pk[j] = f2bf(fmaxf(acc[nb][j] * sc[j] + c2[j], 0.0f));
            *(short4v*)&actOut[(((size_t)b * S_ + s) * 256 + col) * 64 + wv * 16 + lq * 4] = pk;
        }
    }
}

// ---------------------------------------------------------------------------
extern "C" void kernel_launch(void* const* d_in, const int* in_sizes, int n_in,
                              void* d_out, int out_size, void* d_ws, size_t ws_size,
                              hipStream_t stream)
{
    (void)in_sizes; (void)n_in; (void)out_size; (void)ws_size;
    const float* xyz    = (const float*)d_in[0];
    const float* points = (const float*)d_in[1];
    const float* w0 = (const float*)d_in[2];
    const float* b0 = (const float*)d_in[3];
    const float* g0 = (const float*)d_in[4];
    const float* be0 = (const float*)d_in[5];
    const float* m0 = (const float*)d_in[6];
    const float* v0 = (const float*)d_in[7];
    const float* w1 = (const float*)d_in[8];
    const float* b1 = (const float*)d_in[9];
    const float* g1 = (const float*)d_in[10];
    const float* be1 = (const float*)d_in[11];
    const float* m1 = (const float*)d_in[12];
    const float* v1 = (const float*)d_in[13];
    const float* w2 = (const float*)d_in[14];
    const float* b2 = (const float*)d_in[15];
    const float* g2 = (const float*)d_in[16];
    const float* be2 = (const float*)d_in[17];
    const float* m2 = (const float*)d_in[18];
    const float* v2 = (const float*)d_in[19];

    float* out = (float*)d_out;
    char* ws = (char*)d_ws;
    // workspace map:
    //   fidx  @ 0        :   4 KB
    //   gidx  @ 4 KB     :   1 MB
    //   nxyz  @ ~1.05 MB :  96 KB
    //   ptsT  @ 4  MB    : 2.1 MB
    //   actA  @ 8  MB    : 33.6 MB  (ends 41.6 MB)
    //   actB  @ 44 MB    : 33.6 MB  (ends 77.6 MB)
    int*   fidx = (int*)ws;
    int*   gidx = (int*)(ws + 4096);
    float* nxyz = (float*)(ws + 4096 + 16 * 512 * 32 * 4);
    short* ptsT = (short*)(ws + (size_t)(4  * 1024 * 1024));
    short* actA = (short*)(ws + (size_t)(8  * 1024 * 1024));
    short* actB = (short*)(ws + (size_t)(44 * 1024 * 1024));

    transpose_points<<<dim3(16, B_ * T_), 256, 0, stream>>>(points, ptsT);
    fps_kernel<<<B_, 256, 0, stream>>>(xyz, fidx);
    ballquery_kernel<<<dim3(S_, B_ * T_), 64, 0, stream>>>(xyz, fidx, gidx, nxyz, out);

    conv_mfma<67, 104, 3, true, false><<<dim3(S_, B_, 1), 256, 0, stream>>>(
        nullptr, xyz, ptsT, gidx, nxyz, w0, b0, g0, be0, m0, v0, actA, nullptr);
    conv_mfma<64, 72, 2, false, false><<<dim3(S_, B_, 1), 256, 0, stream>>>(
        actA, nullptr, nullptr, nullptr, nullptr, w1, b1, g1, be1, m1, v1, actB, nullptr);
    conv_mfma<64, 72, 2, false, true><<<dim3(S_, B_, 2), 256, 0, stream>>>(
        actB, nullptr, nullptr, nullptr, nullptr, w2, b2, g2, be2, m2, v2, nullptr,
        out + (size_t)B_ * T_ * 3 * S_);
}

// Round 8
// 344.960 us; speedup vs baseline: 1.7440x; 1.7440x over previous
//
#include <hip/hip_runtime.h>
#include <math.h>

#define NPTS 1024
#define S_   512
#define T_   8
#define K_   32
#define B_   2

typedef short bf16x8 __attribute__((ext_vector_type(8)));
typedef short short4v __attribute__((ext_vector_type(4)));
typedef float f32x4 __attribute__((ext_vector_type(4)));
typedef float vf2 __attribute__((ext_vector_type(2)));

static __device__ __forceinline__ short f2bf(float f) {
    unsigned u = __float_as_uint(f);
    unsigned r = (u + 0x7FFFu + ((u >> 16) & 1u)) >> 16;   // RNE
    return (short)r;
}

// ---- DPP wave-64 max reduction helper (result valid in lane 63) -----------
template <int CTRL>
static __device__ __forceinline__ float dppmaxf(float x) {
    int mv = __builtin_amdgcn_update_dpp(0, __float_as_int(x), CTRL, 0xF, 0xF, true);
    return fmaxf(x, __int_as_float(mv));
}
static __device__ __forceinline__ unsigned wavemax_bits_f(float x) {
    x = dppmaxf<0x111>(x); x = dppmaxf<0x112>(x);
    x = dppmaxf<0x114>(x); x = dppmaxf<0x118>(x);
    x = dppmaxf<0x142>(x); x = dppmaxf<0x143>(x);
    return (unsigned)__builtin_amdgcn_readlane(__float_as_int(x), 63);
}

static __device__ __forceinline__ vf2 pk_sub(vf2 a, vf2 b) { return a - b; }
static __device__ __forceinline__ vf2 pk_fma(vf2 a, vf2 b, vf2 c) {
#if __has_builtin(__builtin_elementwise_fma)
    return __builtin_elementwise_fma(a, b, c);
#else
    vf2 r; r[0] = __fmaf_rn(a[0], b[0], c[0]); r[1] = __fmaf_rn(a[1], b[1], c[1]); return r;
#endif
}
static __device__ __forceinline__ vf2 pk_min(vf2 a, vf2 b) {
#if __has_builtin(__builtin_elementwise_min)
    return __builtin_elementwise_min(a, b);
#else
    vf2 r; r[0] = fminf(a[0], b[0]); r[1] = fminf(a[1], b[1]); return r;
#endif
}
static __device__ __forceinline__ vf2 pk_max(vf2 a, vf2 b) {
#if __has_builtin(__builtin_elementwise_max)
    return __builtin_elementwise_max(a, b);
#else
    vf2 r; r[0] = fmaxf(a[0], b[0]); r[1] = fmaxf(a[1], b[1]); return r;
#endif
}

// ---------------------------------------------------------------------------
// Kernel 1: FPS, single wave, lane-major mapping n = lane*16 + j.
// HW-verified r7 (output 0 passed => index sequence bit-exact).
// ---------------------------------------------------------------------------
__global__ __launch_bounds__(64) void fps_kernel(const float* __restrict__ xyz,
                                                 int* __restrict__ fidx)
{
    int b    = blockIdx.x;
    int lane = threadIdx.x;
    __shared__ float4 sc[NPTS];
    const float* bx = xyz + (size_t)b * (T_ * 3 * NPTS);   // frame 0 of batch b
    vf2 px2[8], py2[8], pz2[8], mind2[8];
#pragma unroll
    for (int q = 0; q < 4; ++q) {
        float4 vx = ((const float4*)(bx))[lane * 4 + q];
        float4 vy = ((const float4*)(bx + NPTS))[lane * 4 + q];
        float4 vz = ((const float4*)(bx + 2 * NPTS))[lane * 4 + q];
        px2[q*2]   = (vf2){vx.x, vx.y};  px2[q*2+1] = (vf2){vx.z, vx.w};
        py2[q*2]   = (vf2){vy.x, vy.y};  py2[q*2+1] = (vf2){vy.z, vy.w};
        pz2[q*2]   = (vf2){vz.x, vz.y};  pz2[q*2+1] = (vf2){vz.z, vz.w};
        int n0 = lane * 16 + q * 4;
        sc[n0+0] = make_float4(vx.x, vy.x, vz.x, 0.f);
        sc[n0+1] = make_float4(vx.y, vy.y, vz.y, 0.f);
        sc[n0+2] = make_float4(vx.z, vy.z, vz.z, 0.f);
        sc[n0+3] = make_float4(vx.w, vy.w, vz.w, 0.f);
        mind2[q*2] = (vf2){1e10f, 1e10f}; mind2[q*2+1] = (vf2){1e10f, 1e10f};
    }
    __syncthreads();

    int far = 0;
    for (int it = 0; it < S_; ++it) {
        if (lane == 0) fidx[b * S_ + it] = far;
        float4 c = sc[far];
        vf2 c2x = (vf2){c.x, c.x}, c2y = (vf2){c.y, c.y}, c2z = (vf2){c.z, c.z};
#pragma unroll
        for (int q = 0; q < 8; ++q) {
            vf2 dx = pk_sub(px2[q], c2x);
            vf2 dy = pk_sub(py2[q], c2y);
            vf2 dz = pk_sub(pz2[q], c2z);
            vf2 d  = pk_fma(dz, dz, pk_fma(dy, dy, dx * dx));
            mind2[q] = pk_min(mind2[q], d);
        }
        vf2 t4a = pk_max(mind2[0], mind2[4]);
        vf2 t4b = pk_max(mind2[1], mind2[5]);
        vf2 t4c = pk_max(mind2[2], mind2[6]);
        vf2 t4d = pk_max(mind2[3], mind2[7]);
        vf2 t2a = pk_max(t4a, t4c);
        vf2 t2b = pk_max(t4b, t4d);
        vf2 t1  = pk_max(t2a, t2b);
        float lmax = fmaxf(t1[0], t1[1]);
        unsigned maxb = wavemax_bits_f(lmax);
        int cj[16];
#pragma unroll
        for (int j = 0; j < 16; ++j)
            cj[j] = (__float_as_uint(mind2[j >> 1][j & 1]) == maxb) ? j : 64;
        int m8[8], m4[4], m2v[2];
#pragma unroll
        for (int j = 0; j < 8; ++j) m8[j] = min(cj[j], cj[j + 8]);
#pragma unroll
        for (int j = 0; j < 4; ++j) m4[j] = min(m8[j], m8[j + 4]);
        m2v[0] = min(m4[0], m4[2]); m2v[1] = min(m4[1], m4[3]);
        int minj = min(m2v[0], m2v[1]);
        unsigned long long mk = __ballot(minj < 64);
        int l0 = __ffsll((long long)mk) - 1;     // lowest lane = smallest n
        int jw = __builtin_amdgcn_readlane(minj, l0);
        far = l0 * 16 + jw;
    }
}

// ---------------------------------------------------------------------------
// Kernel 1b: transpose points [bt][64][1024] f32 -> ptsT [bt][1024][64] bf16.
// ---------------------------------------------------------------------------
__global__ __launch_bounds__(256) void transpose_points(
    const float* __restrict__ pts, short* __restrict__ ptsT)
{
    int nt = blockIdx.x;      // 16 tiles of 64 points
    int bt = blockIdx.y;
    __shared__ float tile[64][65];
    int tid = threadIdx.x;
    for (int e = tid; e < 4096; e += 256) {
        int ci = e >> 6, nn = e & 63;
        tile[ci][nn] = pts[((size_t)bt * 64 + ci) * NPTS + nt * 64 + nn];
    }
    __syncthreads();
    for (int e = tid; e < 4096; e += 256) {
        int nn = e >> 6, ci = e & 63;
        ptsT[((size_t)bt * NPTS + nt * 64 + nn) * 64 + ci] = f2bf(tile[ci][nn]);
    }
}

// ---------------------------------------------------------------------------
// Kernel 1c: preconvert weights fp32 -> bf16 global, layout [dt][CO][CIp],
// FULL CO range (fixes r7 bug: layer 3 has CO=128).
// ---------------------------------------------------------------------------
template <int CI, int CIp, int CO, bool PERM>
__global__ __launch_bounds__(256) void prep_w(const float* __restrict__ w,
                                              short* __restrict__ wg)
{
    int e = blockIdx.x * 256 + threadIdx.x;
    if (e >= 4 * CO * CIp) return;
    int dt = e / (CO * CIp);
    int rem = e - dt * (CO * CIp);
    int co = rem / CIp;
    int ci = rem - co * CIp;
    float val = 0.0f;
    if (PERM) {
        int cref = (ci < 64) ? (ci + 3) : ((ci < 67) ? (ci - 64) : -1);
        if (cref >= 0) val = w[((size_t)co * CI + cref) * 4 + dt];
    } else {
        if (ci < CI) val = w[((size_t)co * CI + ci) * 4 + dt];
    }
    wg[e] = f2bf(val);
}

// ---------------------------------------------------------------------------
// Kernel 2: ball query per (bt, s). 1 wave per block (unchanged, verified).
// ---------------------------------------------------------------------------
__global__ void ballquery_kernel(const float* __restrict__ xyz,
                                 const int* __restrict__ fidx,
                                 int* __restrict__ gidx,
                                 float* __restrict__ newxyz,
                                 float* __restrict__ out0)
{
    int s    = blockIdx.x;
    int bt   = blockIdx.y;
    int b    = bt >> 3;
    int lane = threadIdx.x;
    const float* bx = xyz + (size_t)bt * 3 * NPTS;
    int fid = fidx[b * S_ + s];
    float nx = bx[fid], ny = bx[NPTS + fid], nz = bx[2 * NPTS + fid];
    if (lane < 3) {
        float vv = (lane == 0) ? nx : ((lane == 1) ? ny : nz);
        out0[(bt * 3 + lane) * S_ + s]   = vv;   // [B,t,3,S]
        newxyz[(bt * S_ + s) * 3 + lane] = vv;
    }
    float A = __fmaf_rn(nz, nz, __fmaf_rn(ny, ny, __fmul_rn(nx, nx)));
    const float R2 = (float)(0.2 * 0.2);
    int* g = gidx + (size_t)(bt * S_ + s) * K_;
    int count = 0, firstIdx = -1;
    for (int j = 0; j < 16; ++j) {
        if (count >= K_) break;
        int n = j * 64 + lane;
        float x = bx[n], y = bx[NPTS + n], z = bx[2 * NPTS + n];
        float Bn = __fmaf_rn(z, z, __fmaf_rn(y, y, __fmul_rn(x, x)));
        float C  = __fmaf_rn(nz, z, __fmaf_rn(ny, y, __fmul_rn(nx, x)));
        float sq = __fsub_rn(__fadd_rn(A, Bn), __fmul_rn(2.0f, C));
        bool valid = !(sq > R2);
        unsigned long long mb = __ballot(valid);
        if (valid) {
            int pos = count + __popcll(mb & ((1ull << lane) - 1ull));
            if (pos < K_) g[pos] = n;
        }
        if (firstIdx < 0 && mb) firstIdx = j * 64 + (__ffsll((long long)mb) - 1);
        count += __popcll(mb);
    }
    if (count < K_) {
        for (int p = count + lane; p < K_; p += 64) g[p] = firstIdx;
    }
}

// ---------------------------------------------------------------------------
// MFMA conv (verified math). Weights from preconverted bf16 global
// [dt][CO][CIp] with co_base offset; LDS holds only the x tile.
// ---------------------------------------------------------------------------
template <int CI, int CIp, int NK, int CO, bool GATHER, bool POOL>
__global__ __launch_bounds__(256) void conv_mfma(
    const short* __restrict__ actIn,
    const float* __restrict__ xyz, const short* __restrict__ ptsT,
    const int* __restrict__ gidx, const float* __restrict__ newxyz,
    const short* __restrict__ wg, const float* __restrict__ bb,
    const float* __restrict__ gg, const float* __restrict__ be,
    const float* __restrict__ mm, const float* __restrict__ vv,
    short* __restrict__ actOut, float* __restrict__ outPool)
{
    __shared__ __align__(16) short xs[256 * CIp];
    int s = blockIdx.x, b = blockIdx.y;
    int co_base = blockIdx.z * 64;
    int tid = threadIdx.x;

    // ---- stage x tile: xs[col][ci'] bf16, col = t*32 + k ----
    {
        int col = tid;
        short* xrow = &xs[col * CIp];
        if (GATHER) {
            int k = col & 31, tt = col >> 5;
            int bt = b * T_ + tt;
            int idx = gidx[((size_t)bt * S_ + s) * K_ + k];
            const short* prow = ptsT + ((size_t)bt * NPTS + idx) * 64;
#pragma unroll
            for (int c = 0; c < 8; ++c)   // 64 bf16 point channels
                ((int4*)xrow)[c] = ((const int4*)prow)[c];
            const float* nxp = &newxyz[((size_t)bt * S_ + s) * 3];
#pragma unroll
            for (int ci = 0; ci < 3; ++ci)
                xrow[64 + ci] = f2bf(xyz[(size_t)(bt * 3 + ci) * NPTS + idx] - nxp[ci]);
            for (int ci = 67; ci < CIp; ++ci) xrow[ci] = 0;
        } else {
            const short* src = actIn + (((size_t)b * S_ + s) * 256 + col) * 64;
#pragma unroll
            for (int c = 0; c < 8; ++c)   // 8 x 16B = 64 bf16 channels
                ((int4*)xrow)[c] = ((const int4*)src)[c];
            for (int ci = 64; ci < CIp; ++ci) xrow[ci] = 0;
        }
    }
    __syncthreads();

    int lane = tid & 63;
    int wv   = tid >> 6;          // wave id 0..3 -> co stripe
    int l16  = lane & 15;
    int lq   = lane >> 4;

    f32x4 acc[16];
#pragma unroll
    for (int nb = 0; nb < 16; ++nb) acc[nb] = (f32x4){0.f, 0.f, 0.f, 0.f};

#pragma unroll
    for (int ks = 0; ks < NK; ++ks) {
        bf16x8 afr[4];
#pragma unroll
        for (int dt = 0; dt < 4; ++dt)
            afr[dt] = *(const bf16x8*)&wg[((size_t)(dt * CO + co_base + wv * 16 + l16)) * CIp + ks * 32 + lq * 8];
        bf16x8 bfr[16];
#pragma unroll
        for (int cb = 0; cb < 16; ++cb)
            bfr[cb] = *(const bf16x8*)&xs[(cb * 16 + l16) * CIp + ks * 32 + lq * 8];
#pragma unroll
        for (int dt = 0; dt < 4; ++dt) {
#pragma unroll
            for (int nb = 0; nb < 16; ++nb) {
                int cb = nb + (dt - 1) * 2;
                if (cb >= 0 && cb < 16)
                    acc[nb] = __builtin_amdgcn_mfma_f32_16x16x32_bf16(
                        afr[dt], bfr[cb], acc[nb], 0, 0, 0);
            }
        }
    }

    // ---- epilogue: BN + ReLU (+ pool) ----
    float sc[4], c2[4];
#pragma unroll
    for (int j = 0; j < 4; ++j) {
        int co = co_base + wv * 16 + lq * 4 + j;
        float scv = gg[co] / sqrtf(vv[co] + 1e-5f);
        sc[j] = scv;
        c2[j] = (bb[co] - mm[co]) * scv + be[co];
    }

    if (POOL) {
#pragma unroll
        for (int nbp = 0; nbp < 8; ++nbp) {       // t = nbp
#pragma unroll
            for (int j = 0; j < 4; ++j) {
                float v0 = fmaxf(acc[2 * nbp][j] * sc[j] + c2[j], 0.0f);
                float v1 = fmaxf(acc[2 * nbp + 1][j] * sc[j] + c2[j], 0.0f);
                float v = fmaxf(v0, v1);
#pragma unroll
                for (int off = 1; off < 16; off <<= 1)
                    v = fmaxf(v, __shfl_xor(v, off));
                if (l16 == 0) {
                    int co = co_base + wv * 16 + lq * 4 + j;
                    outPool[((size_t)(b * T_ + nbp) * 128 + co) * S_ + s] = v;
                }
            }
        }
    } else {
#pragma unroll
        for (int nb = 0; nb < 16; ++nb) {
            int col = nb * 16 + l16;
            short4v pk;
#pragma unroll
            for (int j = 0; j < 4; ++j)
                pk[j] = f2bf(fmaxf(acc[nb][j] * sc[j] + c2[j], 0.0f));
            *(short4v*)&actOut[(((size_t)b * S_ + s) * 256 + col) * 64 + wv * 16 + lq * 4] = pk;
        }
    }
}

// ---------------------------------------------------------------------------
extern "C" void kernel_launch(void* const* d_in, const int* in_sizes, int n_in,
                              void* d_out, int out_size, void* d_ws, size_t ws_size,
                              hipStream_t stream)
{
    (void)in_sizes; (void)n_in; (void)out_size; (void)ws_size;
    const float* xyz    = (const float*)d_in[0];
    const float* points = (const float*)d_in[1];
    const float* w0 = (const float*)d_in[2];
    const float* b0 = (const float*)d_in[3];
    const float* g0 = (const float*)d_in[4];
    const float* be0 = (const float*)d_in[5];
    const float* m0 = (const float*)d_in[6];
    const float* v0 = (const float*)d_in[7];
    const float* w1 = (const float*)d_in[8];
    const float* b1 = (const float*)d_in[9];
    const float* g1 = (const float*)d_in[10];
    const float* be1 = (const float*)d_in[11];
    const float* m1 = (const float*)d_in[12];
    const float* v1 = (const float*)d_in[13];
    const float* w2 = (const float*)d_in[14];
    const float* b2 = (const float*)d_in[15];
    const float* g2 = (const float*)d_in[16];
    const float* be2 = (const float*)d_in[17];
    const float* m2 = (const float*)d_in[18];
    const float* v2 = (const float*)d_in[19];

    float* out = (float*)d_out;
    char* ws = (char*)d_ws;
    // workspace map:
    //   fidx  @ 0        :   4 KB
    //   gidx  @ 4 KB     :   1 MB
    //   nxyz  @ ~1.05 MB :  96 KB
    //   wg0   @ 3 MB     :  52 KB (4*64*104 bf16)
    //   wg1   @ 3.25 MB  :  36 KB (4*64*72)
    //   wg2   @ 3.5 MB   :  72 KB (4*128*72)
    //   ptsT  @ 4  MB    : 2.1 MB
    //   actA  @ 8  MB    : 33.6 MB  (ends 41.6 MB)
    //   actB  @ 44 MB    : 33.6 MB  (ends 77.6 MB)
    int*   fidx = (int*)ws;
    int*   gidx = (int*)(ws + 4096);
    float* nxyz = (float*)(ws + 4096 + 16 * 512 * 32 * 4);
    short* wg0  = (short*)(ws + (size_t)(3 * 1024 * 1024));
    short* wg1  = (short*)(ws + (size_t)(3 * 1024 * 1024) + 256 * 1024);
    short* wg2  = (short*)(ws + (size_t)(3 * 1024 * 1024) + 512 * 1024);
    short* ptsT = (short*)(ws + (size_t)(4  * 1024 * 1024));
    short* actA = (short*)(ws + (size_t)(8  * 1024 * 1024));
    short* actB = (short*)(ws + (size_t)(44 * 1024 * 1024));

    prep_w<67, 104, 64,  true ><<<(4 * 64  * 104 + 255) / 256, 256, 0, stream>>>(w0, wg0);
    prep_w<64, 72,  64,  false><<<(4 * 64  * 72  + 255) / 256, 256, 0, stream>>>(w1, wg1);
    prep_w<64, 72,  128, false><<<(4 * 128 * 72  + 255) / 256, 256, 0, stream>>>(w2, wg2);
    transpose_points<<<dim3(16, B_ * T_), 256, 0, stream>>>(points, ptsT);
    fps_kernel<<<B_, 64, 0, stream>>>(xyz, fidx);
    ballquery_kernel<<<dim3(S_, B_ * T_), 64, 0, stream>>>(xyz, fidx, gidx, nxyz, out);

    conv_mfma<67, 104, 3, 64, true, false><<<dim3(S_, B_, 1), 256, 0, stream>>>(
        nullptr, xyz, ptsT, gidx, nxyz, wg0, b0, g0, be0, m0, v0, actA, nullptr);
    conv_mfma<64, 72, 2, 64, false, false><<<dim3(S_, B_, 1), 256, 0, stream>>>(
        actA, nullptr, nullptr, nullptr, nullptr, wg1, b1, g1, be1, m1, v1, actB, nullptr);
    conv_mfma<64, 72, 2, 128, false, true><<<dim3(S_, B_, 2), 256, 0, stream>>>(
        actB, nullptr, nullptr, nullptr, nullptr, wg2, b2, g2, be2, m2, v2, nullptr,
        out + (size_t)B_ * T_ * 3 * S_);
}